// Round 4
// baseline (186.202 us; speedup 1.0000x reference)
//
#include <hip/hip_runtime.h>
#include <cstdint>

// ModConv: y[b,o,l] = sum_{i,k} bw[b,o,i,k] * x[b,i,l+k-1],
//   bw = conv_w * s[b,i] * demod[b,o],  s = t@mod_w^T + mod_b + 1,
//   demod = rsqrt(sum_{i,k} (conv_w*s)^2 + 1e-8)
// A-fragments (modulated weights) live in REGISTERS (48 VGPR/lane, computed
// once in the prologue with per-lane demod via shfl reduce). LDS holds only
// the double-buffered 130-row X^T tile (halo included -> no edge fixup, no
// epilogue). 512 thr / 8 waves (4m x 2n), 2 blocks/CU, 1 barrier per tile.

namespace {
constexpr int NI = 128, NO = 256, NK = 3, NT = 256, NL = 8192;
constexpr int BM = 64, BN = 128, TPB = 8;     // block: 64 o x 1024 l
constexpr int BUF_BYTES = 130 * 256;          // 33280 per XT buffer
constexpr int S_OFF = 2 * BUF_BYTES;          // 66560
constexpr int SMEM_BYTES = S_OFF + 512;       // 67072 -> 2 blocks/CU
}

typedef __attribute__((ext_vector_type(8))) short bf16x8;
typedef __attribute__((ext_vector_type(4))) float f32x4;

__device__ __forceinline__ uint32_t f2bf(float f) {
    uint32_t u = __builtin_bit_cast(uint32_t, f);
    return (u + 0x7fffu + ((u >> 16) & 1u)) >> 16;   // RNE
}

__launch_bounds__(512, 4)
__global__ void modconv(const float* __restrict__ x,
                        const float* __restrict__ tvec,
                        const float* __restrict__ conv_w,
                        const float* __restrict__ mod_w,
                        const float* __restrict__ mod_b,
                        float* __restrict__ out) {
    __shared__ __align__(16) char smem[SMEM_BYTES];
    float* s_sh = reinterpret_cast<float*>(smem + S_OFF);

    const int tid = threadIdx.x;

    // 4 o-tile partner blocks of one (b,chunk) share bid&7 (XCD) for x reuse
    const int bid  = blockIdx.x;
    const int slot = bid >> 3;
    const int m    = slot & 3;
    const int g    = (bid & 7) + 8 * (slot >> 2);
    const int b     = g >> 3;
    const int chunk = g & 7;
    const int o0    = m * BM;
    const int C     = chunk * (TPB * BN);

    const float* xb = x + (size_t)b * NI * NL;
    float* outb     = out + ((size_t)b * NO + o0) * NL;

    // ---- XT staging: rows 2+p*32+lrow <-> cols base+p*32+lrow, 8 i per thread
    float xr[4][8];
    const int lrow = tid & 31, ig = tid >> 5;

    auto issue_loads = [&](int base) {
        #pragma unroll
        for (int p = 0; p < 4; ++p) {
            const int col = base + p * 32 + lrow;
            const bool ok = col < NL;
            const float* px = xb + (size_t)(ig * 8) * NL + col;
            #pragma unroll
            for (int n = 0; n < 8; ++n) xr[p][n] = ok ? px[(size_t)n * NL] : 0.f;
        }
    };
    auto write_stage = [&](char* buf) {
        #pragma unroll
        for (int p = 0; p < 4; ++p) {
            const int r = 2 + p * 32 + lrow;
            uint32_t d0 = f2bf(xr[p][0]) | (f2bf(xr[p][1]) << 16);
            uint32_t d1 = f2bf(xr[p][2]) | (f2bf(xr[p][3]) << 16);
            uint32_t d2 = f2bf(xr[p][4]) | (f2bf(xr[p][5]) << 16);
            uint32_t d3 = f2bf(xr[p][6]) | (f2bf(xr[p][7]) << 16);
            *reinterpret_cast<uint4*>(
                buf + r * 256 + ((ig * 16) ^ ((r & 15) << 4))) =
                make_uint4(d0, d1, d2, d3);
        }
    };

    issue_loads(C + 1);   // tile-0 body flies under the whole prologue

    // ---- s[i] = dot(t[b], mod_w[i]) + mod_b[i] + 1   (4 thr/i, f32)
    {
        const int i = tid >> 2, q = tid & 3;
        const float* tp = tvec + b * NT + q * 64;
        const float* mp = mod_w + (size_t)i * NT + q * 64;
        float acc = 0.f;
        #pragma unroll 8
        for (int j = 0; j < 64; ++j) acc = fmaf(tp[j], mp[j], acc);
        acc += __shfl_xor(acc, 1);
        acc += __shfl_xor(acc, 2);
        if (q == 0) s_sh[i] = acc + mod_b[i] + 1.0f;
    }
    __syncthreads();

    const int lane = tid & 63, wid = tid >> 6;
    const int wm = wid >> 1, wn = wid & 1;     // 4m x 2n waves, 16o x 64l each
    const int l16 = lane & 15, lg4 = lane >> 4;
    const int o_l = wm * 16 + l16;             // this lane's output row (local)

    // ---- demod for this lane's o row (exact f32; reduce over lg4 group)
    float dmod;
    {
        float part = 0.f;
        #pragma unroll
        for (int kc = 0; kc < 4; ++kc) {
            const int i0 = kc * 32 + lg4 * 8;
            const f32x4* wp4 = reinterpret_cast<const f32x4*>(
                conv_w + ((size_t)(o0 + o_l) * NI + i0) * NK);
            f32x4 w4[6];
            #pragma unroll
            for (int q = 0; q < 6; ++q) w4[q] = wp4[q];
            #pragma unroll
            for (int j = 0; j < 8; ++j) {
                const float sj = s_sh[i0 + j];
                const float w0 = w4[(j * 3 + 0) >> 2][(j * 3 + 0) & 3];
                const float w1 = w4[(j * 3 + 1) >> 2][(j * 3 + 1) & 3];
                const float w2 = w4[(j * 3 + 2) >> 2][(j * 3 + 2) & 3];
                part = fmaf(sj * sj, w0 * w0 + w1 * w1 + w2 * w2, part);
            }
        }
        part += __shfl_xor(part, 16);   // union over lg4 slices = all 128 i
        part += __shfl_xor(part, 32);
        dmod = rsqrtf(part + 1e-8f);
    }

    // ---- A fragments into registers: afr[k][kc] = bw[o_l][i-slice][k] bf16
    bf16x8 afr[3][4];
    #pragma unroll
    for (int kc = 0; kc < 4; ++kc) {
        const int i0 = kc * 32 + lg4 * 8;
        const f32x4* wp4 = reinterpret_cast<const f32x4*>(
            conv_w + ((size_t)(o0 + o_l) * NI + i0) * NK);
        f32x4 w4[6];
        #pragma unroll
        for (int q = 0; q < 6; ++q) w4[q] = wp4[q];
        #pragma unroll
        for (int j = 0; j < 8; ++j) {
            const float sd = s_sh[i0 + j] * dmod;
            #pragma unroll
            for (int k = 0; k < 3; ++k)
                afr[k][kc][j] =
                    (short)f2bf(w4[(j * 3 + k) >> 2][(j * 3 + k) & 3] * sd);
        }
    }

    // ---- tile-0 halo rows 0,1 (cols C-1, C); C-1 = -1 only for chunk 0
    if (tid < 256) {
        const int i = tid >> 1, wq = tid & 1;
        const int col = C - 1 + wq;
        const float v = (col >= 0) ? xb[(size_t)i * NL + col] : 0.f;
        *reinterpret_cast<uint16_t*>(smem + wq * 256 + ((2 * i) ^ (wq << 4))) =
            (uint16_t)f2bf(v);
    }
    write_stage(smem);      // buf0 rows 2..129 (drains tile-0 loads)
    __syncthreads();

    for (int tile = 0; tile < TPB; ++tile) {
        const int l0  = C + tile * BN;
        const int cur = tile & 1;
        char* rb = smem + cur * BUF_BYTES;
        char* wb = smem + (cur ^ 1) * BUF_BYTES;

        if (tile + 1 < TPB) issue_loads(l0 + 129);   // next tile under MFMA

        f32x4 acc[4];
        const f32x4 zero = {0.f, 0.f, 0.f, 0.f};
        #pragma unroll
        for (int fn = 0; fn < 4; ++fn) acc[fn] = zero;

        __builtin_amdgcn_s_setprio(1);
        #pragma unroll
        for (int k = 0; k < 3; ++k) {
            #pragma unroll
            for (int kc = 0; kc < 4; ++kc) {
                const int cb = kc * 64 + lg4 * 16;
                #pragma unroll
                for (int fn = 0; fn < 4; ++fn) {
                    const int r = wn * 64 + fn * 16 + l16 + k;   // halo shift
                    const bf16x8 bfr = *reinterpret_cast<const bf16x8*>(
                        rb + r * 256 + (cb ^ ((r & 15) << 4)));
                    acc[fn] = __builtin_amdgcn_mfma_f32_16x16x32_bf16(
                        afr[k][kc], bfr, acc[fn], 0, 0, 0);
                }
            }
        }
        __builtin_amdgcn_s_setprio(0);

        // ---- C store (f32, NT): row = wm*16+lg4*4+j, col = l0+wn*64+fn*16+l16
        #pragma unroll
        for (int fn = 0; fn < 4; ++fn) {
            const int colg = l0 + wn * 64 + fn * 16 + l16;
            const int og = wm * 16 + lg4 * 4;
            #pragma unroll
            for (int j = 0; j < 4; ++j)
                __builtin_nontemporal_store(
                    acc[fn][j], &outb[(size_t)(og + j) * NL + colg]);
        }

        if (tile + 1 < TPB) {
            // halo: rows 128,129 of current tile == rows 0,1 of next tile
            if (tid < 32) {
                const int r01 = tid >> 4, c16 = tid & 15;
                const int off = (c16 * 16) ^ (r01 << 4);
                *reinterpret_cast<uint4*>(wb + r01 * 256 + off) =
                    *reinterpret_cast<const uint4*>(rb + (128 + r01) * 256 + off);
            }
            write_stage(wb);          // drains the loads issued before MFMA
        }
        __syncthreads();
    }
}

extern "C" void kernel_launch(void* const* d_in, const int* in_sizes, int n_in,
                              void* d_out, int out_size, void* d_ws, size_t ws_size,
                              hipStream_t stream) {
    const float* x      = (const float*)d_in[0];
    const float* t      = (const float*)d_in[1];
    const float* conv_w = (const float*)d_in[2];
    const float* mod_w  = (const float*)d_in[3];
    const float* mod_b  = (const float*)d_in[4];

    // 4 o-tiles x 8 chunks x 16 b = 512 blocks, 2 per CU
    modconv<<<dim3(512), dim3(512), 0, stream>>>(x, t, conv_w, mod_w, mod_b,
                                                 (float*)d_out);
}

// Round 5
// 126.903 us; speedup vs baseline: 1.4673x; 1.4673x over previous
//
#include <hip/hip_runtime.h>
#include <cstdint>

// ModConv: y[b,o,l] = sum_{i,k} bw[b,o,i,k] * x[b,i,l+k-1],
//   bw = conv_w * s[b,i] * demod[b,o],  s = t@mod_w^T + mod_b + 1,
//   demod = rsqrt(sum_{i,k} (conv_w*s)^2 + 1e-8)
// A-fragments (modulated weights) in REGISTERS (48 VGPR/lane, per-lane demod
// via shfl). LDS = double-buffered 130-row X^T tile only (67 KB). Two xr
// register sets give a 2-deep global->reg->LDS pipeline: tile t+2 issues
// before tile t's MFMA, so HBM never drains. 512 thr / 8 waves (4m x 2n),
// launch_bounds(512,2) -> 256 VGPR cap (round 4 spilled at the 128 cap).
// Grid 256 = 1 block/CU, TPB=16. 4 o-tile partner blocks share an XCD.

namespace {
constexpr int NI = 128, NO = 256, NK = 3, NT = 256, NL = 8192;
constexpr int BM = 64, BN = 128, TPB = 16;    // block: 64 o x 2048 l
constexpr int BUF_BYTES = 130 * 256;          // 33280 per XT buffer
constexpr int S_OFF = 2 * BUF_BYTES;          // 66560
constexpr int SMEM_BYTES = S_OFF + 512;       // 67072
}

typedef __attribute__((ext_vector_type(8))) short bf16x8;
typedef __attribute__((ext_vector_type(4))) float f32x4;

__device__ __forceinline__ uint32_t f2bf(float f) {
    uint32_t u = __builtin_bit_cast(uint32_t, f);
    return (u + 0x7fffu + ((u >> 16) & 1u)) >> 16;   // RNE
}

__launch_bounds__(512, 2)
__global__ void modconv(const float* __restrict__ x,
                        const float* __restrict__ tvec,
                        const float* __restrict__ conv_w,
                        const float* __restrict__ mod_w,
                        const float* __restrict__ mod_b,
                        float* __restrict__ out) {
    __shared__ __align__(16) char smem[SMEM_BYTES];
    float* s_sh = reinterpret_cast<float*>(smem + S_OFF);

    const int tid = threadIdx.x;

    // 4 o-tile partner blocks of one (b,chunk) share bid&7 (XCD) for x reuse
    const int bid  = blockIdx.x;
    const int slot = bid >> 3;                    // [0,32)
    const int m    = slot & 3;                    // o-tile
    const int g    = (bid & 7) + 8 * (slot >> 2); // [0,64) = (b,chunk)
    const int b     = g >> 2;
    const int chunk = g & 3;
    const int o0    = m * BM;
    const int C     = chunk * (TPB * BN);         // 2048-col chunk

    const float* xb = x + (size_t)b * NI * NL;
    float* outb     = out + ((size_t)b * NO + o0) * NL;

    // ---- XT staging: row r=2+p*32+lrow <-> col base+p*32+lrow, 8 i/thread
    float xrA[4][8], xrB[4][8];
    const int lrow = tid & 31, ig = tid >> 5;

    auto issueL = [&](float (&xr)[4][8], int base) {
        #pragma unroll
        for (int p = 0; p < 4; ++p) {
            const int col = base + p * 32 + lrow;
            const bool ok = col < NL;             // col 8192 only (chunk 3 tail)
            const float* px = xb + (size_t)(ig * 8) * NL + col;
            #pragma unroll
            for (int n = 0; n < 8; ++n) xr[p][n] = ok ? px[(size_t)n * NL] : 0.f;
        }
    };
    auto writeS = [&](char* buf, float (&xr)[4][8]) {
        #pragma unroll
        for (int p = 0; p < 4; ++p) {
            const int r = 2 + p * 32 + lrow;
            uint32_t d0 = f2bf(xr[p][0]) | (f2bf(xr[p][1]) << 16);
            uint32_t d1 = f2bf(xr[p][2]) | (f2bf(xr[p][3]) << 16);
            uint32_t d2 = f2bf(xr[p][4]) | (f2bf(xr[p][5]) << 16);
            uint32_t d3 = f2bf(xr[p][6]) | (f2bf(xr[p][7]) << 16);
            *reinterpret_cast<uint4*>(
                buf + r * 256 + ((ig * 16) ^ ((r & 15) << 4))) =
                make_uint4(d0, d1, d2, d3);
        }
    };

    issueL(xrA, C + 1);   // tile-0 body flies under the whole prologue

    // ---- s[i] = dot(t[b], mod_w[i]) + mod_b[i] + 1   (4 thr/i, f32)
    {
        const int i = tid >> 2, q = tid & 3;
        const float* tp = tvec + b * NT + q * 64;
        const float* mp = mod_w + (size_t)i * NT + q * 64;
        float acc = 0.f;
        #pragma unroll 8
        for (int j = 0; j < 64; ++j) acc = fmaf(tp[j], mp[j], acc);
        acc += __shfl_xor(acc, 1);
        acc += __shfl_xor(acc, 2);
        if (q == 0) s_sh[i] = acc + mod_b[i] + 1.0f;
    }
    __syncthreads();

    const int lane = tid & 63, wid = tid >> 6;
    const int wm = wid >> 1, wn = wid & 1;     // 4m x 2n waves, 16o x 64l each
    const int l16 = lane & 15, lg4 = lane >> 4;
    const int o_l = wm * 16 + l16;             // this lane's output row (local)

    // ---- demod for this lane's o row (exact f32; reduce across lg4 groups)
    float dmod;
    {
        float part = 0.f;
        #pragma unroll
        for (int kc = 0; kc < 4; ++kc) {
            const int i0 = kc * 32 + lg4 * 8;
            const f32x4* wp4 = reinterpret_cast<const f32x4*>(
                conv_w + ((size_t)(o0 + o_l) * NI + i0) * NK);
            f32x4 w4[6];
            #pragma unroll
            for (int q = 0; q < 6; ++q) w4[q] = wp4[q];
            #pragma unroll
            for (int j = 0; j < 8; ++j) {
                const float sj = s_sh[i0 + j];
                const float w0 = w4[(j * 3 + 0) >> 2][(j * 3 + 0) & 3];
                const float w1 = w4[(j * 3 + 1) >> 2][(j * 3 + 1) & 3];
                const float w2 = w4[(j * 3 + 2) >> 2][(j * 3 + 2) & 3];
                part = fmaf(sj * sj, w0 * w0 + w1 * w1 + w2 * w2, part);
            }
        }
        part += __shfl_xor(part, 16);
        part += __shfl_xor(part, 32);
        dmod = rsqrtf(part + 1e-8f);
    }

    // ---- A fragments into registers: afr[k][kc] = bw[o_l][i-slice][k] bf16
    bf16x8 afr[3][4];
    #pragma unroll
    for (int kc = 0; kc < 4; ++kc) {
        const int i0 = kc * 32 + lg4 * 8;
        const f32x4* wp4 = reinterpret_cast<const f32x4*>(
            conv_w + ((size_t)(o0 + o_l) * NI + i0) * NK);
        f32x4 w4[6];
        #pragma unroll
        for (int q = 0; q < 6; ++q) w4[q] = wp4[q];
        #pragma unroll
        for (int j = 0; j < 8; ++j) {
            const float sd = s_sh[i0 + j] * dmod;
            #pragma unroll
            for (int k = 0; k < 3; ++k)
                afr[k][kc][j] =
                    (short)f2bf(w4[(j * 3 + k) >> 2][(j * 3 + k) & 3] * sd);
        }
    }

    // ---- tile-0 halo rows 0,1 (cols C-1, C); C-1 < 0 only for chunk 0
    if (tid < 256) {
        const int i = tid >> 1, wq = tid & 1;
        const int col = C - 1 + wq;
        const float v = (col >= 0) ? xb[(size_t)i * NL + col] : 0.f;
        *reinterpret_cast<uint16_t*>(smem + wq * 256 + ((2 * i) ^ (wq << 4))) =
            (uint16_t)f2bf(v);
    }
    writeS(smem, xrA);        // buf0 rows 2..129 (drains tile-0 loads)
    issueL(xrB, C + BN + 1);  // tile-1 loads fly under tile-0 MFMA
    __syncthreads();

    auto body = [&](int t, float (&xrT)[4][8], float (&xrN)[4][8]) {
        const int l0 = C + t * BN;
        char* rb = smem + (t & 1) * BUF_BYTES;
        char* wb = smem + ((t & 1) ^ 1) * BUF_BYTES;

        if (t + 2 < TPB) issueL(xrT, l0 + 2 * BN + 1);   // t+2: keep HBM fed
        if (t + 1 < TPB) {
            if (tid < 32) {   // halo: rb rows 128,129 == wb rows 0,1
                const int r01 = tid >> 4, c16 = tid & 15;
                const int off = (c16 * 16) ^ (r01 << 4);
                *reinterpret_cast<uint4*>(wb + r01 * 256 + off) =
                    *reinterpret_cast<const uint4*>(rb + (128 + r01) * 256 + off);
            }
            writeS(wb, xrN);  // waits only t+1's loads (issued a tile ago)
        }

        f32x4 acc[4];
        const f32x4 zero = {0.f, 0.f, 0.f, 0.f};
        #pragma unroll
        for (int fn = 0; fn < 4; ++fn) acc[fn] = zero;

        __builtin_amdgcn_s_setprio(1);
        #pragma unroll
        for (int k = 0; k < 3; ++k) {
            #pragma unroll
            for (int kc = 0; kc < 4; ++kc) {
                const int cb = kc * 64 + lg4 * 16;
                #pragma unroll
                for (int fn = 0; fn < 4; ++fn) {
                    const int r = wn * 64 + fn * 16 + l16 + k;   // halo shift
                    const bf16x8 bfr = *reinterpret_cast<const bf16x8*>(
                        rb + r * 256 + (cb ^ ((r & 15) << 4)));
                    acc[fn] = __builtin_amdgcn_mfma_f32_16x16x32_bf16(
                        afr[k][kc], bfr, acc[fn], 0, 0, 0);
                }
            }
        }
        __builtin_amdgcn_s_setprio(0);

        // C store: row = wm*16+lg4*4+j, col = l0+wn*64+fn*16+l16
        #pragma unroll
        for (int fn = 0; fn < 4; ++fn) {
            const int colg = l0 + wn * 64 + fn * 16 + l16;
            const int og = wm * 16 + lg4 * 4;
            #pragma unroll
            for (int j = 0; j < 4; ++j)
                __builtin_nontemporal_store(
                    acc[fn][j], &outb[(size_t)(og + j) * NL + colg]);
        }
        __syncthreads();
    };

    #pragma unroll 1
    for (int t = 0; t < TPB; t += 2) {
        body(t,     xrA, xrB);
        body(t + 1, xrB, xrA);
    }
}

extern "C" void kernel_launch(void* const* d_in, const int* in_sizes, int n_in,
                              void* d_out, int out_size, void* d_ws, size_t ws_size,
                              hipStream_t stream) {
    const float* x      = (const float*)d_in[0];
    const float* t      = (const float*)d_in[1];
    const float* conv_w = (const float*)d_in[2];
    const float* mod_w  = (const float*)d_in[3];
    const float* mod_b  = (const float*)d_in[4];

    // 4 o-tiles x 4 chunks x 16 b = 256 blocks = 1 per CU
    modconv<<<dim3(256), dim3(512), 0, stream>>>(x, t, conv_w, mod_w, mod_b,
                                                 (float*)d_out);
}